// Round 10
// baseline (300.242 us; speedup 1.0000x reference)
//
#include <hip/hip_runtime.h>

// ---------------------------------------------------------------------------
// MDNV2 fused kernels for MI355X (gfx950) — round 10
//
// Base = round 7 (best, 207 us). Changes:
//  * pair_kernel tile 64 -> 128 rows (halves DS ops + weight staging per row).
//  * Weight panel staged via __builtin_amdgcn_global_load_lds (width 16):
//    no register round-trip (-36 VGPR), DMA overlaps the X-build.
//  * All outputs stored nontemporal -> output stream stops evicting
//    Pq/W2q from L2.
// fp8 e4m3 GEMM2 (weights x16), bf16 Lq/Pq as round 7.
// ---------------------------------------------------------------------------

typedef __attribute__((ext_vector_type(4))) float f32x4;
typedef __attribute__((ext_vector_type(4))) unsigned int u32x4;
typedef __attribute__((ext_vector_type(8))) short bf16x8;

#define M_TOT 327680
#define WSCALE 16.0f
#define WDESCALE 0.0625f

__device__ __forceinline__ unsigned short f2bf(float f) {
    union { float f; unsigned int u; } v; v.f = f;
    unsigned int r = (v.u + 0x7FFFu + ((v.u >> 16) & 1u)) >> 16;  // RNE
    return (unsigned short)r;
}

__device__ __forceinline__ float eluf(float y) {
    return fmaxf(y, 0.f) + __expf(fminf(y, 0.f)) - 1.f;
}

__device__ __forceinline__ float bfhalf_lo(unsigned int u) {
    return __uint_as_float(u << 16);
}
__device__ __forceinline__ float bfhalf_hi(unsigned int u) {
    return __uint_as_float(u & 0xFFFF0000u);
}

// ---------------------------------------------------------------------------
// prep_weights (+ folded tail): ws layout (bytes):
//   W1T @0      : [256 n][256 k] bf16                                131072
//   W2q @131072 : fp8 [head 3][f 9][sp 4][lane 64][h 2][j 8]         110592
//   b2s @241664 : [3][144] f32 (bias x16, pads zero)                   1728
//   a1  @243392 : [256] f32
//   cs  @244416 : [256] f32
//   Lq  @245440 : [768][256] bf16
//   Pq  @638656 : [6144][256] bf16  (3 MB -> L2-resident)
// ---------------------------------------------------------------------------
__global__ void prep_weights(const float* __restrict__ W1, const float* __restrict__ b1,
                             const float* __restrict__ gamma, const float* __restrict__ beta,
                             const float* __restrict__ rmean, const float* __restrict__ rvar,
                             const float* __restrict__ Wpi, const float* __restrict__ bpi,
                             const float* __restrict__ Wsig, const float* __restrict__ bsig,
                             const float* __restrict__ Wmu, const float* __restrict__ bmu,
                             const float* __restrict__ h_l,
                             const int* __restrict__ esrc, const int* __restrict__ edst,
                             const float* __restrict__ Wat, const float* __restrict__ bat,
                             const float* __restrict__ Wbt, const float* __restrict__ bbt,
                             unsigned short* __restrict__ W1T, unsigned char* __restrict__ W2q,
                             float* __restrict__ b2s, float* __restrict__ a1v, float* __restrict__ csv,
                             float* __restrict__ out_at, float* __restrict__ out_bt) {
    int idx = blockIdx.x * 256 + threadIdx.x;          // 432 blocks -> 110592
    {
        int j    = idx & 7;
        int h    = (idx >> 3) & 1;
        int lane = (idx >> 4) & 63;
        int sp   = (idx >> 10) & 3;
        int t    = idx >> 12;                          // 0..26
        int f    = t % 9;
        int head = t / 9;
        int k    = (sp * 2 + h) * 32 + (lane >> 4) * 8 + j;
        int col  = f * 16 + (lane & 15);
        float v = 0.f;
        if (col < 140) {
            const float* Wh = (head == 0) ? Wpi : (head == 1) ? Wsig : Wmu;
            v = Wh[k * 140 + col] * WSCALE;
        }
        W2q[idx] = (unsigned char)(__builtin_amdgcn_cvt_pk_fp8_f32(v, 0.f, 0, false) & 0xFF);
    }
    if (idx < 256 * 256) {                             // W1T[n][k] = W1[k][n]
        int n = idx >> 8, k = idx & 255;
        W1T[idx] = f2bf(W1[k * 256 + n]);
    }
    if (idx < 432) {                                   // b2s[head][col]
        int head = idx / 144, col = idx % 144;
        float v = 0.f;
        if (col < 140) v = (head == 0) ? bpi[col] : (head == 1) ? bsig[col] : bmu[col];
        b2s[idx] = v * WSCALE;
    }
    if (idx < 256) {
        float s = gamma[idx] * rsqrtf(rvar[idx] + 1e-5f);
        a1v[idx] = s;
        csv[idx] = s * (b1[idx] - rmean[idx]) + beta[idx];
    }
    // ---- folded tail: atom_types [768,17], bond_types [2048,5] ----
    if (idx < 768 * 17) {
        int row = idx / 17, c = idx % 17;
        const float* hr = h_l + (size_t)row * 128;
        float s = bat[c];
        #pragma unroll 4
        for (int k = 0; k < 128; ++k) s += hr[k] * Wat[k * 17 + c];
        out_at[idx] = s;
    } else if (idx < 768 * 17 + 2048 * 5) {
        int t2 = idx - 768 * 17;
        int e = t2 / 5, c = t2 % 5;
        const float* hs = h_l + (size_t)esrc[e] * 128;
        const float* hd = h_l + (size_t)edst[e] * 128;
        float s = bbt[c];
        #pragma unroll 4
        for (int k = 0; k < 128; ++k)
            s += hs[k] * Wbt[k * 5 + c] + hd[k] * Wbt[(k + 128) * 5 + c];
        out_bt[t2] = s;
    }
}

// ---------------------------------------------------------------------------
// node_gemm: Lq (BN shift folded) / Pq (scale only), bf16 output
// ---------------------------------------------------------------------------
__global__ __launch_bounds__(256, 2) void node_gemm(
        const float* __restrict__ h_l, const float* __restrict__ h_p,
        const unsigned short* __restrict__ W1T,
        const float* __restrict__ a1v, const float* __restrict__ csv,
        unsigned short* __restrict__ Lq, unsigned short* __restrict__ Pq) {
    const int tid = threadIdx.x, lane = tid & 63, w = tid >> 6;
    const int cGrp = lane & 15, g = lane >> 4;
    const int row0 = blockIdx.x * 64;
    const bool isLig = row0 < 768;
    const float* src = isLig ? (h_l + (size_t)row0 * 128) : (h_p + (size_t)(row0 - 768) * 128);
    unsigned short* dst = isLig ? (Lq + (size_t)row0 * 256) : (Pq + (size_t)(row0 - 768) * 256);
    const int koff = isLig ? 0 : 128;

    f32x4 acc[16];
    #pragma unroll
    for (int fn = 0; fn < 16; ++fn) acc[fn] = (f32x4){0.f, 0.f, 0.f, 0.f};

    #pragma unroll
    for (int fk = 0; fk < 4; ++fk) {
        const float* ap = src + (size_t)(w * 16 + cGrp) * 128 + fk * 32 + g * 8;
        f32x4 qa = *(const f32x4*)ap;
        f32x4 qb = *(const f32x4*)(ap + 4);
        bf16x8 af;
        af[0] = (short)f2bf(qa[0]); af[1] = (short)f2bf(qa[1]);
        af[2] = (short)f2bf(qa[2]); af[3] = (short)f2bf(qa[3]);
        af[4] = (short)f2bf(qb[0]); af[5] = (short)f2bf(qb[1]);
        af[6] = (short)f2bf(qb[2]); af[7] = (short)f2bf(qb[3]);
        #pragma unroll
        for (int fn = 0; fn < 16; ++fn) {
            bf16x8 bf = *(const bf16x8*)(W1T + (fn * 16 + cGrp) * 256 + koff + fk * 32 + g * 8);
            acc[fn] = __builtin_amdgcn_mfma_f32_16x16x32_bf16(af, bf, acc[fn], 0, 0, 0);
        }
    }
    #pragma unroll
    for (int fn = 0; fn < 16; ++fn) {
        int h = fn * 16 + cGrp;
        float s = a1v[h];
        float c0 = isLig ? csv[h] : 0.f;
        #pragma unroll
        for (int rg = 0; rg < 4; ++rg)
            dst[(size_t)(w * 16 + g * 4 + rg) * 256 + h] = f2bf(s * acc[fn][rg] + c0);
    }
}

// ---------------------------------------------------------------------------
// pair_kernel: grid (2560, 3 heads), block 256 (4 waves).
// Tile = 128 rows x 144 cols; wave = 2 rowsets of 16 rows x 144 cols.
// Weight panel (36.9 KB) staged via global_load_lds; outputs nontemporal.
// ---------------------------------------------------------------------------
__global__ __launch_bounds__(256, 4) void pair_kernel(
        const unsigned short* __restrict__ Lq, const unsigned short* __restrict__ Pq,
        const unsigned char* __restrict__ W2q, const float* __restrict__ b2s,
        const float* __restrict__ lig_pos, const float* __restrict__ prot_pos,
        float* __restrict__ out_pi, float* __restrict__ out_sig, float* __restrict__ out_mu,
        float* __restrict__ out_dist, float* __restrict__ out_pb) {

    __shared__ __align__(16) unsigned char Bs[36864];

    const int tid = threadIdx.x, lane = tid & 63, w = tid >> 6;
    const int c = lane & 15, g = lane >> 4;
    const int head = blockIdx.y;
    const int m0 = blockIdx.x * 128;

    // ---- closed-form pair decode (128-row tile: one batch + ligand run) ----
    unsigned int P = (unsigned int)m0 / 40960u;
    unsigned int r = (unsigned int)m0 % 40960u;
    int b, cl, cp0;
    if (r < 8192u) {            // even batch: 32 lig x 256 prot
        b = 2 * (int)P; cl = 96 * (int)P + (int)(r >> 8); cp0 = 768 * (int)P + (int)(r & 255u);
    } else {                    // odd batch: 64 lig x 512 prot
        unsigned int rr = r - 8192u;
        b = 2 * (int)P + 1; cl = 96 * (int)P + 32 + (int)(rr >> 9);
        cp0 = 768 * (int)P + 256 + (int)(rr & 511u);
    }

    // ---- async weight staging: wave w DMAs 1 KB per chunk, 9 chunks ----
    const unsigned char* wsrc = W2q + (size_t)head * 36864;
    #pragma unroll
    for (int i = 0; i < 9; ++i) {
        const unsigned char* gp = wsrc + i * 4096 + w * 1024 + (lane << 4);
        __builtin_amdgcn_global_load_lds(
            (const __attribute__((address_space(1))) void*)gp,
            (__attribute__((address_space(3))) void*)(Bs + i * 4096 + w * 1024),
            16, 0, 0);
    }

    // ---- bias (x16 prescaled) ----
    float bb[9];
    #pragma unroll
    for (int f = 0; f < 9; ++f) bb[f] = b2s[head * 144 + f * 16 + c];

    // ---- X = fp8(elu(Lq+Pq)) for 2 rowsets, A-fragment layout ----
    const unsigned short* lqp = Lq + (size_t)cl * 256;
    long Xa[16];                                  // [rs*8 + 2*sp + h]
    #pragma unroll
    for (int rs = 0; rs < 2; ++rs) {
        const int row = rs * 64 + w * 16 + c;
        const unsigned short* pqp = Pq + (size_t)(cp0 + row) * 256;
        #pragma unroll
        for (int s = 0; s < 8; ++s) {
            u32x4 pv = *(const u32x4*)(pqp + s * 32 + g * 8);
            u32x4 lv = *(const u32x4*)(lqp + s * 32 + g * 8);
            float y0 = eluf(bfhalf_lo(pv[0]) + bfhalf_lo(lv[0]));
            float y1 = eluf(bfhalf_hi(pv[0]) + bfhalf_hi(lv[0]));
            float y2 = eluf(bfhalf_lo(pv[1]) + bfhalf_lo(lv[1]));
            float y3 = eluf(bfhalf_hi(pv[1]) + bfhalf_hi(lv[1]));
            float y4 = eluf(bfhalf_lo(pv[2]) + bfhalf_lo(lv[2]));
            float y5 = eluf(bfhalf_hi(pv[2]) + bfhalf_hi(lv[2]));
            float y6 = eluf(bfhalf_lo(pv[3]) + bfhalf_lo(lv[3]));
            float y7 = eluf(bfhalf_hi(pv[3]) + bfhalf_hi(lv[3]));
            unsigned int lo = (unsigned int)__builtin_amdgcn_cvt_pk_fp8_f32(y0, y1, 0, false);
            lo = (unsigned int)__builtin_amdgcn_cvt_pk_fp8_f32(y2, y3, (int)lo, true);
            unsigned int hi = (unsigned int)__builtin_amdgcn_cvt_pk_fp8_f32(y4, y5, 0, false);
            hi = (unsigned int)__builtin_amdgcn_cvt_pk_fp8_f32(y6, y7, (int)hi, true);
            Xa[rs * 8 + s] = (long)(((unsigned long long)hi << 32) | (unsigned long long)lo);
        }
    }

    __syncthreads();    // drains the global_load_lds DMA (vmcnt) + barrier

    // ---- K-loop: 36 ds_read_b128 feed 144 fp8 MFMAs ----
    f32x4 acc[9][2];
    #pragma unroll
    for (int f = 0; f < 9; ++f) {
        acc[f][0] = (f32x4){bb[f], bb[f], bb[f], bb[f]};
        acc[f][1] = acc[f][0];
    }

    #pragma unroll
    for (int sp = 0; sp < 4; ++sp) {
        #pragma unroll
        for (int f = 0; f < 9; ++f) {
            u32x4 bq = *(const u32x4*)(Bs + f * 4096 + sp * 1024 + lane * 16);
            long b0 = (long)(((unsigned long long)bq[1] << 32) | (unsigned long long)bq[0]);
            long b1 = (long)(((unsigned long long)bq[3] << 32) | (unsigned long long)bq[2]);
            acc[f][0] = __builtin_amdgcn_mfma_f32_16x16x32_fp8_fp8(Xa[2 * sp],     b0, acc[f][0], 0, 0, 0);
            acc[f][0] = __builtin_amdgcn_mfma_f32_16x16x32_fp8_fp8(Xa[2 * sp + 1], b1, acc[f][0], 0, 0, 0);
            acc[f][1] = __builtin_amdgcn_mfma_f32_16x16x32_fp8_fp8(Xa[8 + 2 * sp],     b0, acc[f][1], 0, 0, 0);
            acc[f][1] = __builtin_amdgcn_mfma_f32_16x16x32_fp8_fp8(Xa[8 + 2 * sp + 1], b1, acc[f][1], 0, 0, 0);
        }
    }

    // ---- de-scale ----
    #pragma unroll
    for (int f = 0; f < 9; ++f)
        #pragma unroll
        for (int rs = 0; rs < 2; ++rs)
            #pragma unroll
            for (int q = 0; q < 4; ++q) acc[f][rs][q] *= WDESCALE;

    const bool v8 = (c < 12);   // frag 8 covers cols 128..143, valid < 140

    if (head == 0) {
        // ---- pi: softmax over 140 cols, 16-lane-group local ----
        #pragma unroll
        for (int rs = 0; rs < 2; ++rs) {
            #pragma unroll
            for (int q = 0; q < 4; ++q) {
                float mx = fmaxf(fmaxf(fmaxf(acc[0][rs][q], acc[1][rs][q]), fmaxf(acc[2][rs][q], acc[3][rs][q])),
                                 fmaxf(fmaxf(acc[4][rs][q], acc[5][rs][q]), fmaxf(acc[6][rs][q], acc[7][rs][q])));
                if (v8) mx = fmaxf(mx, acc[8][rs][q]);
                mx = fmaxf(mx, __shfl_xor(mx, 1, 64));
                mx = fmaxf(mx, __shfl_xor(mx, 2, 64));
                mx = fmaxf(mx, __shfl_xor(mx, 4, 64));
                mx = fmaxf(mx, __shfl_xor(mx, 8, 64));
                float e0 = __expf(acc[0][rs][q] - mx), e1 = __expf(acc[1][rs][q] - mx);
                float e2 = __expf(acc[2][rs][q] - mx), e3 = __expf(acc[3][rs][q] - mx);
                float e4 = __expf(acc[4][rs][q] - mx), e5 = __expf(acc[5][rs][q] - mx);
                float e6 = __expf(acc[6][rs][q] - mx), e7 = __expf(acc[7][rs][q] - mx);
                float e8 = v8 ? __expf(acc[8][rs][q] - mx) : 0.f;
                float sm = ((e0 + e1) + (e2 + e3)) + ((e4 + e5) + (e6 + e7)) + e8;
                sm += __shfl_xor(sm, 1, 64);
                sm += __shfl_xor(sm, 2, 64);
                sm += __shfl_xor(sm, 4, 64);
                sm += __shfl_xor(sm, 8, 64);
                float inv = 1.f / sm;
                const int gr = m0 + rs * 64 + w * 16 + g * 4 + q;
                float* prow = out_pi + (size_t)gr * 140;
                __builtin_nontemporal_store(e0 * inv, prow + c);
                __builtin_nontemporal_store(e1 * inv, prow + 16 + c);
                __builtin_nontemporal_store(e2 * inv, prow + 32 + c);
                __builtin_nontemporal_store(e3 * inv, prow + 48 + c);
                __builtin_nontemporal_store(e4 * inv, prow + 64 + c);
                __builtin_nontemporal_store(e5 * inv, prow + 80 + c);
                __builtin_nontemporal_store(e6 * inv, prow + 96 + c);
                __builtin_nontemporal_store(e7 * inv, prow + 112 + c);
                if (v8) __builtin_nontemporal_store(e8 * inv, prow + 128 + c);
            }
        }
    } else {
        const float addc = (head == 1) ? 1.1f : 1.0f;
        float* outh = (head == 1) ? out_sig : out_mu;
        #pragma unroll
        for (int rs = 0; rs < 2; ++rs) {
            #pragma unroll
            for (int q = 0; q < 4; ++q) {
                const int gr = m0 + rs * 64 + w * 16 + g * 4 + q;
                float* row = outh + (size_t)gr * 140;
                __builtin_nontemporal_store(eluf(acc[0][rs][q]) + addc, row + c);
                __builtin_nontemporal_store(eluf(acc[1][rs][q]) + addc, row + 16 + c);
                __builtin_nontemporal_store(eluf(acc[2][rs][q]) + addc, row + 32 + c);
                __builtin_nontemporal_store(eluf(acc[3][rs][q]) + addc, row + 48 + c);
                __builtin_nontemporal_store(eluf(acc[4][rs][q]) + addc, row + 64 + c);
                __builtin_nontemporal_store(eluf(acc[5][rs][q]) + addc, row + 80 + c);
                __builtin_nontemporal_store(eluf(acc[6][rs][q]) + addc, row + 96 + c);
                __builtin_nontemporal_store(eluf(acc[7][rs][q]) + addc, row + 112 + c);
                if (v8) __builtin_nontemporal_store(eluf(acc[8][rs][q]) + addc, row + 128 + c);
            }
        }
        if (head == 2) {
            // ---- dist + pb ----
            float lx = lig_pos[cl * 3 + 0];
            float ly = lig_pos[cl * 3 + 1];
            float lz = lig_pos[cl * 3 + 2];
            #pragma unroll
            for (int i = 0; i < 7; ++i) {
                int idx = tid + 256 * i;                  // < 1792 = 128*14
                int rw = idx / 14, a = idx - rw * 14;
                const float* pp = prot_pos + (size_t)(cp0 + rw) * 42 + a * 3;
                float dx = lx - pp[0], dy = ly - pp[1], dz = lz - pp[2];
                __builtin_nontemporal_store(sqrtf(dx * dx + dy * dy + dz * dz),
                                            out_dist + (size_t)(m0 + rw) * 14 + a);
            }
            if (tid < 128) __builtin_nontemporal_store((float)b, out_pb + m0 + tid);
        }
    }
}

// ---------------------------------------------------------------------------
extern "C" void kernel_launch(void* const* d_in, const int* in_sizes, int n_in,
                              void* d_out, int out_size, void* d_ws, size_t ws_size,
                              hipStream_t stream) {
    const float* h_l      = (const float*)d_in[0];
    const float* h_p      = (const float*)d_in[1];
    const float* lig_pos  = (const float*)d_in[2];
    const float* prot_pos = (const float*)d_in[3];
    const int*   esrc     = (const int*)d_in[4];
    const int*   edst     = (const int*)d_in[5];
    const float* W1    = (const float*)d_in[12];
    const float* b1    = (const float*)d_in[13];
    const float* gamma = (const float*)d_in[14];
    const float* beta  = (const float*)d_in[15];
    const float* rmean = (const float*)d_in[16];
    const float* rvar  = (const float*)d_in[17];
    const float* Wpi   = (const float*)d_in[18];
    const float* bpi   = (const float*)d_in[19];
    const float* Wsig  = (const float*)d_in[20];
    const float* bsig  = (const float*)d_in[21];
    const float* Wmu   = (const float*)d_in[22];
    const float* bmu   = (const float*)d_in[23];
    const float* Wat   = (const float*)d_in[24];
    const float* bat   = (const float*)d_in[25];
    const float* Wbt   = (const float*)d_in[26];
    const float* bbt   = (const float*)d_in[27];

    char* ws = (char*)d_ws;
    unsigned short* W1T = (unsigned short*)(ws + 0);
    unsigned char*  W2q = (unsigned char*)(ws + 131072);
    float*          b2s = (float*)(ws + 241664);
    float*          a1v = (float*)(ws + 243392);
    float*          csv = (float*)(ws + 244416);
    unsigned short* Lq  = (unsigned short*)(ws + 245440);
    unsigned short* Pq  = (unsigned short*)(ws + 638656);

    float* out = (float*)d_out;
    const size_t M = M_TOT;
    float* out_pi   = out;
    float* out_sig  = out + M * 140;
    float* out_mu   = out + 2 * M * 140;
    float* out_dist = out + 3 * M * 140;
    float* out_at   = out + 3 * M * 140 + M * 14;
    float* out_bt   = out_at + 768 * 17;
    float* out_pb   = out_bt + 2048 * 5;

    hipLaunchKernelGGL(prep_weights, dim3(432), dim3(256), 0, stream,
                       W1, b1, gamma, beta, rmean, rvar,
                       Wpi, bpi, Wsig, bsig, Wmu, bmu,
                       h_l, esrc, edst, Wat, bat, Wbt, bbt,
                       W1T, W2q, b2s, a1v, csv, out_at, out_bt);

    hipLaunchKernelGGL(node_gemm, dim3((768 + 6144) / 64), dim3(256), 0, stream,
                       h_l, h_p, W1T, a1v, csv, Lq, Pq);

    hipLaunchKernelGGL(pair_kernel, dim3(M_TOT / 128, 3), dim3(256), 0, stream,
                       Lq, Pq, W2q, b2s, lig_pos, prot_pos,
                       out_pi, out_sig, out_mu, out_dist, out_pb);
}

// Round 11
// 211.746 us; speedup vs baseline: 1.4179x; 1.4179x over previous
//
#include <hip/hip_runtime.h>

// ---------------------------------------------------------------------------
// MDNV2 fused kernels for MI355X (gfx950) — round 11
//
// Base = round 7 (best, 207 us). R8 (persistence), R9 (Xq materialization),
// R10 (tile-128 + global_load_lds + NT stores bundle) all regressed; reverted.
// Minimal separable changes vs R7:
//  * dist+pb moved to a dedicated dist_kernel (balances the 3 head blocks).
//  * pair grid flattened: head = bid%3 -> 3 heads of a tile are adjacent
//    dispatches (Pq rows L1/L2-hot for 2 of 3 blocks).
//  * node_gemm split into 2 N-halves (216 blocks, better CU fill).
//  * prep W1 transpose re-indexed for coalesced reads.
// fp8 e4m3 GEMM2 (weights x16), bf16 Lq/Pq as round 7.
// ---------------------------------------------------------------------------

typedef __attribute__((ext_vector_type(4))) float f32x4;
typedef __attribute__((ext_vector_type(4))) unsigned int u32x4;
typedef __attribute__((ext_vector_type(8))) short bf16x8;

#define M_TOT 327680
#define WSCALE 16.0f
#define WDESCALE 0.0625f

__device__ __forceinline__ unsigned short f2bf(float f) {
    union { float f; unsigned int u; } v; v.f = f;
    unsigned int r = (v.u + 0x7FFFu + ((v.u >> 16) & 1u)) >> 16;  // RNE
    return (unsigned short)r;
}

__device__ __forceinline__ float eluf(float y) {
    return fmaxf(y, 0.f) + __expf(fminf(y, 0.f)) - 1.f;
}

__device__ __forceinline__ float bfhalf_lo(unsigned int u) {
    return __uint_as_float(u << 16);
}
__device__ __forceinline__ float bfhalf_hi(unsigned int u) {
    return __uint_as_float(u & 0xFFFF0000u);
}

__device__ __forceinline__ void pair_decode(int m0, int& b, int& cl, int& cp0) {
    unsigned int P = (unsigned int)m0 / 40960u;
    unsigned int r = (unsigned int)m0 % 40960u;
    if (r < 8192u) {            // even batch: 32 lig x 256 prot
        b = 2 * (int)P; cl = 96 * (int)P + (int)(r >> 8); cp0 = 768 * (int)P + (int)(r & 255u);
    } else {                    // odd batch: 64 lig x 512 prot
        unsigned int rr = r - 8192u;
        b = 2 * (int)P + 1; cl = 96 * (int)P + 32 + (int)(rr >> 9);
        cp0 = 768 * (int)P + 256 + (int)(rr & 511u);
    }
}

// ---------------------------------------------------------------------------
// prep_weights (+ folded tail): ws layout (bytes):
//   W1T @0      : [256 n][256 k] bf16                                131072
//   W2q @131072 : fp8 [head 3][f 9][sp 4][lane 64][h 2][j 8]         110592
//   b2s @241664 : [3][144] f32 (bias x16, pads zero)                   1728
//   a1  @243392 : [256] f32
//   cs  @244416 : [256] f32
//   Lq  @245440 : [768][256] bf16
//   Pq  @638656 : [6144][256] bf16  (3 MB -> L2-resident)
// ---------------------------------------------------------------------------
__global__ void prep_weights(const float* __restrict__ W1, const float* __restrict__ b1,
                             const float* __restrict__ gamma, const float* __restrict__ beta,
                             const float* __restrict__ rmean, const float* __restrict__ rvar,
                             const float* __restrict__ Wpi, const float* __restrict__ bpi,
                             const float* __restrict__ Wsig, const float* __restrict__ bsig,
                             const float* __restrict__ Wmu, const float* __restrict__ bmu,
                             const float* __restrict__ h_l,
                             const int* __restrict__ esrc, const int* __restrict__ edst,
                             const float* __restrict__ Wat, const float* __restrict__ bat,
                             const float* __restrict__ Wbt, const float* __restrict__ bbt,
                             unsigned short* __restrict__ W1T, unsigned char* __restrict__ W2q,
                             float* __restrict__ b2s, float* __restrict__ a1v, float* __restrict__ csv,
                             float* __restrict__ out_at, float* __restrict__ out_bt) {
    int idx = blockIdx.x * 256 + threadIdx.x;          // 432 blocks -> 110592
    {
        int j    = idx & 7;
        int h    = (idx >> 3) & 1;
        int lane = (idx >> 4) & 63;
        int sp   = (idx >> 10) & 3;
        int t    = idx >> 12;                          // 0..26
        int f    = t % 9;
        int head = t / 9;
        int k    = (sp * 2 + h) * 32 + (lane >> 4) * 8 + j;
        int col  = f * 16 + (lane & 15);
        float v = 0.f;
        if (col < 140) {
            const float* Wh = (head == 0) ? Wpi : (head == 1) ? Wsig : Wmu;
            v = Wh[k * 140 + col] * WSCALE;
        }
        W2q[idx] = (unsigned char)(__builtin_amdgcn_cvt_pk_fp8_f32(v, 0.f, 0, false) & 0xFF);
    }
    if (idx < 256 * 256) {                             // W1T[n][k] = W1[k][n], coalesced reads
        int n = idx & 255, k = idx >> 8;
        W1T[n * 256 + k] = f2bf(W1[k * 256 + n]);
    }
    if (idx < 432) {                                   // b2s[head][col]
        int head = idx / 144, col = idx % 144;
        float v = 0.f;
        if (col < 140) v = (head == 0) ? bpi[col] : (head == 1) ? bsig[col] : bmu[col];
        b2s[idx] = v * WSCALE;
    }
    if (idx < 256) {
        float s = gamma[idx] * rsqrtf(rvar[idx] + 1e-5f);
        a1v[idx] = s;
        csv[idx] = s * (b1[idx] - rmean[idx]) + beta[idx];
    }
    // ---- folded tail: atom_types [768,17], bond_types [2048,5] ----
    if (idx < 768 * 17) {
        int row = idx / 17, c = idx % 17;
        const float* hr = h_l + (size_t)row * 128;
        float s = bat[c];
        #pragma unroll 4
        for (int k = 0; k < 128; ++k) s += hr[k] * Wat[k * 17 + c];
        out_at[idx] = s;
    } else if (idx < 768 * 17 + 2048 * 5) {
        int t2 = idx - 768 * 17;
        int e = t2 / 5, c = t2 % 5;
        const float* hs = h_l + (size_t)esrc[e] * 128;
        const float* hd = h_l + (size_t)edst[e] * 128;
        float s = bbt[c];
        #pragma unroll 4
        for (int k = 0; k < 128; ++k)
            s += hs[k] * Wbt[k * 5 + c] + hd[k] * Wbt[(k + 128) * 5 + c];
        out_bt[t2] = s;
    }
}

// ---------------------------------------------------------------------------
// node_gemm: Lq (BN shift folded) / Pq (scale only), bf16 output.
// grid 216 = 108 row-blocks x 2 N-halves (8 fragments each).
// ---------------------------------------------------------------------------
__global__ __launch_bounds__(256, 2) void node_gemm(
        const float* __restrict__ h_l, const float* __restrict__ h_p,
        const unsigned short* __restrict__ W1T,
        const float* __restrict__ a1v, const float* __restrict__ csv,
        unsigned short* __restrict__ Lq, unsigned short* __restrict__ Pq) {
    const int tid = threadIdx.x, lane = tid & 63, w = tid >> 6;
    const int cGrp = lane & 15, g = lane >> 4;
    const int nh   = blockIdx.x & 1;
    const int row0 = (blockIdx.x >> 1) * 64;
    const bool isLig = row0 < 768;
    const float* src = isLig ? (h_l + (size_t)row0 * 128) : (h_p + (size_t)(row0 - 768) * 128);
    unsigned short* dst = isLig ? (Lq + (size_t)row0 * 256) : (Pq + (size_t)(row0 - 768) * 256);
    const int koff = isLig ? 0 : 128;

    f32x4 acc[8];
    #pragma unroll
    for (int fn = 0; fn < 8; ++fn) acc[fn] = (f32x4){0.f, 0.f, 0.f, 0.f};

    #pragma unroll
    for (int fk = 0; fk < 4; ++fk) {
        const float* ap = src + (size_t)(w * 16 + cGrp) * 128 + fk * 32 + g * 8;
        f32x4 qa = *(const f32x4*)ap;
        f32x4 qb = *(const f32x4*)(ap + 4);
        bf16x8 af;
        af[0] = (short)f2bf(qa[0]); af[1] = (short)f2bf(qa[1]);
        af[2] = (short)f2bf(qa[2]); af[3] = (short)f2bf(qa[3]);
        af[4] = (short)f2bf(qb[0]); af[5] = (short)f2bf(qb[1]);
        af[6] = (short)f2bf(qb[2]); af[7] = (short)f2bf(qb[3]);
        #pragma unroll
        for (int fn = 0; fn < 8; ++fn) {
            int n = nh * 128 + fn * 16 + cGrp;
            bf16x8 bf = *(const bf16x8*)(W1T + (size_t)n * 256 + koff + fk * 32 + g * 8);
            acc[fn] = __builtin_amdgcn_mfma_f32_16x16x32_bf16(af, bf, acc[fn], 0, 0, 0);
        }
    }
    #pragma unroll
    for (int fn = 0; fn < 8; ++fn) {
        int h = nh * 128 + fn * 16 + cGrp;
        float s = a1v[h];
        float c0 = isLig ? csv[h] : 0.f;
        #pragma unroll
        for (int rg = 0; rg < 4; ++rg)
            dst[(size_t)(w * 16 + g * 4 + rg) * 256 + h] = f2bf(s * acc[fn][rg] + c0);
    }
}

// ---------------------------------------------------------------------------
// dist_kernel: grid 1280, block 256. 256 pair-rows/block (single batch+lig).
// Thread = one pair row: 42 contiguous prot floats in, 14 contiguous out.
// ---------------------------------------------------------------------------
__global__ __launch_bounds__(256, 8) void dist_kernel(
        const float* __restrict__ lig_pos, const float* __restrict__ prot_pos,
        float* __restrict__ out_dist, float* __restrict__ out_pb) {
    const int m0 = blockIdx.x * 256;
    int b, cl, cp0;
    pair_decode(m0, b, cl, cp0);

    const int rw = threadIdx.x;
    float lx = lig_pos[cl * 3 + 0];
    float ly = lig_pos[cl * 3 + 1];
    float lz = lig_pos[cl * 3 + 2];
    const float* pp = prot_pos + (size_t)(cp0 + rw) * 42;
    float* dr = out_dist + (size_t)(m0 + rw) * 14;
    #pragma unroll
    for (int a = 0; a < 14; ++a) {
        float dx = lx - pp[a * 3 + 0];
        float dy = ly - pp[a * 3 + 1];
        float dz = lz - pp[a * 3 + 2];
        dr[a] = sqrtf(dx * dx + dy * dy + dz * dz);
    }
    out_pb[m0 + rw] = (float)b;
}

// ---------------------------------------------------------------------------
// pair_kernel: grid 15360 flat (head = bid%3, tile = bid/3), block 256.
// Tile = 64 rows x 144 cols; wave = 16 rows x 144 cols (9 frags). = R7 core.
// ---------------------------------------------------------------------------
__global__ __launch_bounds__(256, 4) void pair_kernel(
        const unsigned short* __restrict__ Lq, const unsigned short* __restrict__ Pq,
        const unsigned char* __restrict__ W2q, const float* __restrict__ b2s,
        float* __restrict__ out_pi, float* __restrict__ out_sig, float* __restrict__ out_mu) {

    __shared__ __align__(16) unsigned char Bs[36864];

    const int tid = threadIdx.x, lane = tid & 63, w = tid >> 6;
    const int c = lane & 15, g = lane >> 4;
    const unsigned int bid = blockIdx.x;
    const int head = (int)(bid % 3u);
    const int m0   = (int)(bid / 3u) * 64;

    int b, cl, cp0;
    pair_decode(m0, b, cl, cp0);

    // ---- issue weight staging loads (9 x 16B/thread = 36864 B) ----
    const unsigned char* wsrc = W2q + (size_t)head * 36864;
    u32x4 stg[9];
    #pragma unroll
    for (int i = 0; i < 9; ++i)
        stg[i] = *(const u32x4*)(wsrc + (size_t)(tid + 256 * i) * 16);

    // ---- bias (x16 prescaled) ----
    float bb[9];
    #pragma unroll
    for (int f = 0; f < 9; ++f) bb[f] = b2s[head * 144 + f * 16 + c];

    // ---- X = fp8(elu(Lq+Pq)) in registers (A-fragment layout) ----
    const int row = w * 16 + c;
    const unsigned short* pqp = Pq + (size_t)(cp0 + row) * 256;
    const unsigned short* lqp = Lq + (size_t)cl * 256;
    long Xa[8];
    #pragma unroll
    for (int s = 0; s < 8; ++s) {
        u32x4 pv = *(const u32x4*)(pqp + s * 32 + g * 8);
        u32x4 lv = *(const u32x4*)(lqp + s * 32 + g * 8);
        float y0 = eluf(bfhalf_lo(pv[0]) + bfhalf_lo(lv[0]));
        float y1 = eluf(bfhalf_hi(pv[0]) + bfhalf_hi(lv[0]));
        float y2 = eluf(bfhalf_lo(pv[1]) + bfhalf_lo(lv[1]));
        float y3 = eluf(bfhalf_hi(pv[1]) + bfhalf_hi(lv[1]));
        float y4 = eluf(bfhalf_lo(pv[2]) + bfhalf_lo(lv[2]));
        float y5 = eluf(bfhalf_hi(pv[2]) + bfhalf_hi(lv[2]));
        float y6 = eluf(bfhalf_lo(pv[3]) + bfhalf_lo(lv[3]));
        float y7 = eluf(bfhalf_hi(pv[3]) + bfhalf_hi(lv[3]));
        unsigned int lo = (unsigned int)__builtin_amdgcn_cvt_pk_fp8_f32(y0, y1, 0, false);
        lo = (unsigned int)__builtin_amdgcn_cvt_pk_fp8_f32(y2, y3, (int)lo, true);
        unsigned int hi = (unsigned int)__builtin_amdgcn_cvt_pk_fp8_f32(y4, y5, 0, false);
        hi = (unsigned int)__builtin_amdgcn_cvt_pk_fp8_f32(y6, y7, (int)hi, true);
        Xa[s] = (long)(((unsigned long long)hi << 32) | (unsigned long long)lo);
    }

    // ---- write staged weights to LDS, single barrier ----
    #pragma unroll
    for (int i = 0; i < 9; ++i)
        *(u32x4*)(Bs + (size_t)(tid + 256 * i) * 16) = stg[i];
    __syncthreads();

    // ---- K-loop: 36 conflict-free ds_read_b128 + 72 fp8 MFMA ----
    f32x4 acc[9];
    #pragma unroll
    for (int f = 0; f < 9; ++f) acc[f] = (f32x4){bb[f], bb[f], bb[f], bb[f]};

    #pragma unroll
    for (int sp = 0; sp < 4; ++sp) {
        long xa0 = Xa[2 * sp], xa1 = Xa[2 * sp + 1];
        #pragma unroll
        for (int f = 0; f < 9; ++f) {
            u32x4 bq = *(const u32x4*)(Bs + f * 4096 + sp * 1024 + lane * 16);
            long b0 = (long)(((unsigned long long)bq[1] << 32) | (unsigned long long)bq[0]);
            long b1 = (long)(((unsigned long long)bq[3] << 32) | (unsigned long long)bq[2]);
            acc[f] = __builtin_amdgcn_mfma_f32_16x16x32_fp8_fp8(xa0, b0, acc[f], 0, 0, 0);
            acc[f] = __builtin_amdgcn_mfma_f32_16x16x32_fp8_fp8(xa1, b1, acc[f], 0, 0, 0);
        }
    }

    // ---- de-scale ----
    #pragma unroll
    for (int f = 0; f < 9; ++f)
        #pragma unroll
        for (int q = 0; q < 4; ++q) acc[f][q] *= WDESCALE;

    const bool v8 = (c < 12);   // frag 8 covers cols 128..143, valid < 140

    if (head == 0) {
        // ---- pi: softmax over 140 cols, 16-lane-group local ----
        #pragma unroll
        for (int q = 0; q < 4; ++q) {
            float mx = fmaxf(fmaxf(fmaxf(acc[0][q], acc[1][q]), fmaxf(acc[2][q], acc[3][q])),
                             fmaxf(fmaxf(acc[4][q], acc[5][q]), fmaxf(acc[6][q], acc[7][q])));
            if (v8) mx = fmaxf(mx, acc[8][q]);
            mx = fmaxf(mx, __shfl_xor(mx, 1, 64));
            mx = fmaxf(mx, __shfl_xor(mx, 2, 64));
            mx = fmaxf(mx, __shfl_xor(mx, 4, 64));
            mx = fmaxf(mx, __shfl_xor(mx, 8, 64));
            float e0 = __expf(acc[0][q] - mx), e1 = __expf(acc[1][q] - mx);
            float e2 = __expf(acc[2][q] - mx), e3 = __expf(acc[3][q] - mx);
            float e4 = __expf(acc[4][q] - mx), e5 = __expf(acc[5][q] - mx);
            float e6 = __expf(acc[6][q] - mx), e7 = __expf(acc[7][q] - mx);
            float e8 = v8 ? __expf(acc[8][q] - mx) : 0.f;
            float sm = ((e0 + e1) + (e2 + e3)) + ((e4 + e5) + (e6 + e7)) + e8;
            sm += __shfl_xor(sm, 1, 64);
            sm += __shfl_xor(sm, 2, 64);
            sm += __shfl_xor(sm, 4, 64);
            sm += __shfl_xor(sm, 8, 64);
            float inv = 1.f / sm;
            const int gr = m0 + w * 16 + g * 4 + q;
            float* prow = out_pi + (size_t)gr * 140;
            prow[c]       = e0 * inv;  prow[16 + c]  = e1 * inv;
            prow[32 + c]  = e2 * inv;  prow[48 + c]  = e3 * inv;
            prow[64 + c]  = e4 * inv;  prow[80 + c]  = e5 * inv;
            prow[96 + c]  = e6 * inv;  prow[112 + c] = e7 * inv;
            if (v8) prow[128 + c] = e8 * inv;
        }
    } else {
        const float addc = (head == 1) ? 1.1f : 1.0f;
        float* outh = (head == 1) ? out_sig : out_mu;
        #pragma unroll
        for (int q = 0; q < 4; ++q) {
            const int gr = m0 + w * 16 + g * 4 + q;
            float* row = outh + (size_t)gr * 140;
            row[c]       = eluf(acc[0][q]) + addc;
            row[16 + c]  = eluf(acc[1][q]) + addc;
            row[32 + c]  = eluf(acc[2][q]) + addc;
            row[48 + c]  = eluf(acc[3][q]) + addc;
            row[64 + c]  = eluf(acc[4][q]) + addc;
            row[80 + c]  = eluf(acc[5][q]) + addc;
            row[96 + c]  = eluf(acc[6][q]) + addc;
            row[112 + c] = eluf(acc[7][q]) + addc;
            if (v8) row[128 + c] = eluf(acc[8][q]) + addc;
        }
    }
}

// ---------------------------------------------------------------------------
extern "C" void kernel_launch(void* const* d_in, const int* in_sizes, int n_in,
                              void* d_out, int out_size, void* d_ws, size_t ws_size,
                              hipStream_t stream) {
    const float* h_l      = (const float*)d_in[0];
    const float* h_p      = (const float*)d_in[1];
    const float* lig_pos  = (const float*)d_in[2];
    const float* prot_pos = (const float*)d_in[3];
    const int*   esrc     = (const int*)d_in[4];
    const int*   edst     = (const int*)d_in[5];
    const float* W1    = (const float*)d_in[12];
    const float* b1    = (const float*)d_in[13];
    const float* gamma = (const float*)d_in[14];
    const float* beta  = (const float*)d_in[15];
    const float* rmean = (const float*)d_in[16];
    const float* rvar  = (const float*)d_in[17];
    const float* Wpi   = (const float*)d_in[18];
    const float* bpi   = (const float*)d_in[19];
    const float* Wsig  = (const float*)d_in[20];
    const float* bsig  = (const float*)d_in[21];
    const float* Wmu   = (const float*)d_in[22];
    const float* bmu   = (const float*)d_in[23];
    const float* Wat   = (const float*)d_in[24];
    const float* bat   = (const float*)d_in[25];
    const float* Wbt   = (const float*)d_in[26];
    const float* bbt   = (const float*)d_in[27];

    char* ws = (char*)d_ws;
    unsigned short* W1T = (unsigned short*)(ws + 0);
    unsigned char*  W2q = (unsigned char*)(ws + 131072);
    float*          b2s = (float*)(ws + 241664);
    float*          a1v = (float*)(ws + 243392);
    float*          csv = (float*)(ws + 244416);
    unsigned short* Lq  = (unsigned short*)(ws + 245440);
    unsigned short* Pq  = (unsigned short*)(ws + 638656);

    float* out = (float*)d_out;
    const size_t M = M_TOT;
    float* out_pi   = out;
    float* out_sig  = out + M * 140;
    float* out_mu   = out + 2 * M * 140;
    float* out_dist = out + 3 * M * 140;
    float* out_at   = out + 3 * M * 140 + M * 14;
    float* out_bt   = out_at + 768 * 17;
    float* out_pb   = out_bt + 2048 * 5;

    hipLaunchKernelGGL(dist_kernel, dim3(M_TOT / 256), dim3(256), 0, stream,
                       lig_pos, prot_pos, out_dist, out_pb);

    hipLaunchKernelGGL(prep_weights, dim3(432), dim3(256), 0, stream,
                       W1, b1, gamma, beta, rmean, rvar,
                       Wpi, bpi, Wsig, bsig, Wmu, bmu,
                       h_l, esrc, edst, Wat, bat, Wbt, bbt,
                       W1T, W2q, b2s, a1v, csv, out_at, out_bt);

    hipLaunchKernelGGL(node_gemm, dim3(2 * (768 + 6144) / 64), dim3(256), 0, stream,
                       h_l, h_p, W1T, a1v, csv, Lq, Pq);

    hipLaunchKernelGGL(pair_kernel, dim3(3 * M_TOT / 64), dim3(256), 0, stream,
                       Lq, Pq, W2q, b2s, out_pi, out_sig, out_mu);
}

// Round 12
// 204.466 us; speedup vs baseline: 1.4684x; 1.0356x over previous
//
#include <hip/hip_runtime.h>

// ---------------------------------------------------------------------------
// MDNV2 fused kernels for MI355X (gfx950) — round 12
//
// Base = R7/R11 structure. Single lever this round: OCCUPANCY.
//  * pair_kernel: 512 threads (8 waves share ONE 36.9 KB panel), tile=128
//    rows, per-wave work unchanged (16 rows x 144 cols, 9 frags).
//    3 blocks/CU -> 110 KB LDS, 24 waves/CU (6/SIMD) vs R7's 16.
//  * __launch_bounds__(512, 6) caps VGPR at ~85 to realize 6 waves/SIMD.
//  * Weight staging via global_load_lds (0 staging VGPRs, linear layout).
//  * dist_kernel / node_gemm / prep as R11.
// fp8 e4m3 GEMM2 (weights x16), bf16 Lq/Pq.
// ---------------------------------------------------------------------------

typedef __attribute__((ext_vector_type(4))) float f32x4;
typedef __attribute__((ext_vector_type(4))) unsigned int u32x4;
typedef __attribute__((ext_vector_type(8))) short bf16x8;

#define M_TOT 327680
#define WSCALE 16.0f
#define WDESCALE 0.0625f

__device__ __forceinline__ unsigned short f2bf(float f) {
    union { float f; unsigned int u; } v; v.f = f;
    unsigned int r = (v.u + 0x7FFFu + ((v.u >> 16) & 1u)) >> 16;  // RNE
    return (unsigned short)r;
}

__device__ __forceinline__ float eluf(float y) {
    return fmaxf(y, 0.f) + __expf(fminf(y, 0.f)) - 1.f;
}

__device__ __forceinline__ float bfhalf_lo(unsigned int u) {
    return __uint_as_float(u << 16);
}
__device__ __forceinline__ float bfhalf_hi(unsigned int u) {
    return __uint_as_float(u & 0xFFFF0000u);
}

__device__ __forceinline__ void pair_decode(int m0, int& b, int& cl, int& cp0) {
    unsigned int P = (unsigned int)m0 / 40960u;
    unsigned int r = (unsigned int)m0 % 40960u;
    if (r < 8192u) {            // even batch: 32 lig x 256 prot
        b = 2 * (int)P; cl = 96 * (int)P + (int)(r >> 8); cp0 = 768 * (int)P + (int)(r & 255u);
    } else {                    // odd batch: 64 lig x 512 prot
        unsigned int rr = r - 8192u;
        b = 2 * (int)P + 1; cl = 96 * (int)P + 32 + (int)(rr >> 9);
        cp0 = 768 * (int)P + 256 + (int)(rr & 511u);
    }
}

// ---------------------------------------------------------------------------
// prep_weights (+ folded tail): ws layout (bytes):
//   W1T @0      : [256 n][256 k] bf16                                131072
//   W2q @131072 : fp8 [head 3][f 9][sp 4][lane 64][h 2][j 8]         110592
//   b2s @241664 : [3][144] f32 (bias x16, pads zero)                   1728
//   a1  @243392 : [256] f32
//   cs  @244416 : [256] f32
//   Lq  @245440 : [768][256] bf16
//   Pq  @638656 : [6144][256] bf16  (3 MB -> L2-resident)
// ---------------------------------------------------------------------------
__global__ void prep_weights(const float* __restrict__ W1, const float* __restrict__ b1,
                             const float* __restrict__ gamma, const float* __restrict__ beta,
                             const float* __restrict__ rmean, const float* __restrict__ rvar,
                             const float* __restrict__ Wpi, const float* __restrict__ bpi,
                             const float* __restrict__ Wsig, const float* __restrict__ bsig,
                             const float* __restrict__ Wmu, const float* __restrict__ bmu,
                             const float* __restrict__ h_l,
                             const int* __restrict__ esrc, const int* __restrict__ edst,
                             const float* __restrict__ Wat, const float* __restrict__ bat,
                             const float* __restrict__ Wbt, const float* __restrict__ bbt,
                             unsigned short* __restrict__ W1T, unsigned char* __restrict__ W2q,
                             float* __restrict__ b2s, float* __restrict__ a1v, float* __restrict__ csv,
                             float* __restrict__ out_at, float* __restrict__ out_bt) {
    int idx = blockIdx.x * 256 + threadIdx.x;          // 432 blocks -> 110592
    {
        int j    = idx & 7;
        int h    = (idx >> 3) & 1;
        int lane = (idx >> 4) & 63;
        int sp   = (idx >> 10) & 3;
        int t    = idx >> 12;                          // 0..26
        int f    = t % 9;
        int head = t / 9;
        int k    = (sp * 2 + h) * 32 + (lane >> 4) * 8 + j;
        int col  = f * 16 + (lane & 15);
        float v = 0.f;
        if (col < 140) {
            const float* Wh = (head == 0) ? Wpi : (head == 1) ? Wsig : Wmu;
            v = Wh[k * 140 + col] * WSCALE;
        }
        W2q[idx] = (unsigned char)(__builtin_amdgcn_cvt_pk_fp8_f32(v, 0.f, 0, false) & 0xFF);
    }
    if (idx < 256 * 256) {                             // W1T[n][k] = W1[k][n], coalesced reads
        int n = idx & 255, k = idx >> 8;
        W1T[n * 256 + k] = f2bf(W1[k * 256 + n]);
    }
    if (idx < 432) {                                   // b2s[head][col]
        int head = idx / 144, col = idx % 144;
        float v = 0.f;
        if (col < 140) v = (head == 0) ? bpi[col] : (head == 1) ? bsig[col] : bmu[col];
        b2s[idx] = v * WSCALE;
    }
    if (idx < 256) {
        float s = gamma[idx] * rsqrtf(rvar[idx] + 1e-5f);
        a1v[idx] = s;
        csv[idx] = s * (b1[idx] - rmean[idx]) + beta[idx];
    }
    // ---- folded tail: atom_types [768,17], bond_types [2048,5] ----
    if (idx < 768 * 17) {
        int row = idx / 17, c = idx % 17;
        const float* hr = h_l + (size_t)row * 128;
        float s = bat[c];
        #pragma unroll 4
        for (int k = 0; k < 128; ++k) s += hr[k] * Wat[k * 17 + c];
        out_at[idx] = s;
    } else if (idx < 768 * 17 + 2048 * 5) {
        int t2 = idx - 768 * 17;
        int e = t2 / 5, c = t2 % 5;
        const float* hs = h_l + (size_t)esrc[e] * 128;
        const float* hd = h_l + (size_t)edst[e] * 128;
        float s = bbt[c];
        #pragma unroll 4
        for (int k = 0; k < 128; ++k)
            s += hs[k] * Wbt[k * 5 + c] + hd[k] * Wbt[(k + 128) * 5 + c];
        out_bt[t2] = s;
    }
}

// ---------------------------------------------------------------------------
// node_gemm: Lq (BN shift folded) / Pq (scale only), bf16 output.
// grid 216 = 108 row-blocks x 2 N-halves (8 fragments each).
// ---------------------------------------------------------------------------
__global__ __launch_bounds__(256, 2) void node_gemm(
        const float* __restrict__ h_l, const float* __restrict__ h_p,
        const unsigned short* __restrict__ W1T,
        const float* __restrict__ a1v, const float* __restrict__ csv,
        unsigned short* __restrict__ Lq, unsigned short* __restrict__ Pq) {
    const int tid = threadIdx.x, lane = tid & 63, w = tid >> 6;
    const int cGrp = lane & 15, g = lane >> 4;
    const int nh   = blockIdx.x & 1;
    const int row0 = (blockIdx.x >> 1) * 64;
    const bool isLig = row0 < 768;
    const float* src = isLig ? (h_l + (size_t)row0 * 128) : (h_p + (size_t)(row0 - 768) * 128);
    unsigned short* dst = isLig ? (Lq + (size_t)row0 * 256) : (Pq + (size_t)(row0 - 768) * 256);
    const int koff = isLig ? 0 : 128;

    f32x4 acc[8];
    #pragma unroll
    for (int fn = 0; fn < 8; ++fn) acc[fn] = (f32x4){0.f, 0.f, 0.f, 0.f};

    #pragma unroll
    for (int fk = 0; fk < 4; ++fk) {
        const float* ap = src + (size_t)(w * 16 + cGrp) * 128 + fk * 32 + g * 8;
        f32x4 qa = *(const f32x4*)ap;
        f32x4 qb = *(const f32x4*)(ap + 4);
        bf16x8 af;
        af[0] = (short)f2bf(qa[0]); af[1] = (short)f2bf(qa[1]);
        af[2] = (short)f2bf(qa[2]); af[3] = (short)f2bf(qa[3]);
        af[4] = (short)f2bf(qb[0]); af[5] = (short)f2bf(qb[1]);
        af[6] = (short)f2bf(qb[2]); af[7] = (short)f2bf(qb[3]);
        #pragma unroll
        for (int fn = 0; fn < 8; ++fn) {
            int n = nh * 128 + fn * 16 + cGrp;
            bf16x8 bf = *(const bf16x8*)(W1T + (size_t)n * 256 + koff + fk * 32 + g * 8);
            acc[fn] = __builtin_amdgcn_mfma_f32_16x16x32_bf16(af, bf, acc[fn], 0, 0, 0);
        }
    }
    #pragma unroll
    for (int fn = 0; fn < 8; ++fn) {
        int h = nh * 128 + fn * 16 + cGrp;
        float s = a1v[h];
        float c0 = isLig ? csv[h] : 0.f;
        #pragma unroll
        for (int rg = 0; rg < 4; ++rg)
            dst[(size_t)(w * 16 + g * 4 + rg) * 256 + h] = f2bf(s * acc[fn][rg] + c0);
    }
}

// ---------------------------------------------------------------------------
// dist_kernel: grid 1280, block 256. 256 pair-rows/block (single batch+lig).
// ---------------------------------------------------------------------------
__global__ __launch_bounds__(256, 8) void dist_kernel(
        const float* __restrict__ lig_pos, const float* __restrict__ prot_pos,
        float* __restrict__ out_dist, float* __restrict__ out_pb) {
    const int m0 = blockIdx.x * 256;
    int b, cl, cp0;
    pair_decode(m0, b, cl, cp0);

    const int rw = threadIdx.x;
    float lx = lig_pos[cl * 3 + 0];
    float ly = lig_pos[cl * 3 + 1];
    float lz = lig_pos[cl * 3 + 2];
    const float* pp = prot_pos + (size_t)(cp0 + rw) * 42;
    float* dr = out_dist + (size_t)(m0 + rw) * 14;
    #pragma unroll
    for (int a = 0; a < 14; ++a) {
        float dx = lx - pp[a * 3 + 0];
        float dy = ly - pp[a * 3 + 1];
        float dz = lz - pp[a * 3 + 2];
        dr[a] = sqrtf(dx * dx + dy * dy + dz * dz);
    }
    out_pb[m0 + rw] = (float)b;
}

// ---------------------------------------------------------------------------
// pair_kernel: grid (2560, 3 heads), block 512 (8 waves share one panel).
// Tile = 128 rows; wave = 16 rows x 144 cols (9 frags) — per-wave work = R7.
// launch_bounds(512,6): VGPR<=~85 -> 3 blocks/CU = 24 waves/CU (6/SIMD).
// Panel staged via global_load_lds (0 staging VGPRs).
// ---------------------------------------------------------------------------
__global__ __launch_bounds__(512, 6) void pair_kernel(
        const unsigned short* __restrict__ Lq, const unsigned short* __restrict__ Pq,
        const unsigned char* __restrict__ W2q, const float* __restrict__ b2s,
        float* __restrict__ out_pi, float* __restrict__ out_sig, float* __restrict__ out_mu) {

    __shared__ __align__(16) unsigned char Bs[36864];

    const int tid = threadIdx.x, lane = tid & 63, w = tid >> 6;   // w: 0..7
    const int c = lane & 15, g = lane >> 4;
    const int head = blockIdx.y;
    const int m0 = blockIdx.x * 128;

    int b, cl, cp0;
    pair_decode(m0, b, cl, cp0);

    // ---- async panel staging: 36 chunks of 1 KB; wave w takes ch = w+8i ----
    const unsigned char* wsrc = W2q + (size_t)head * 36864;
    #pragma unroll
    for (int i = 0; i < 5; ++i) {
        int ch = w + 8 * i;
        if (ch < 36) {
            const unsigned char* gp = wsrc + ch * 1024 + (lane << 4);
            __builtin_amdgcn_global_load_lds(
                (const __attribute__((address_space(1))) void*)gp,
                (__attribute__((address_space(3))) void*)(Bs + ch * 1024),
                16, 0, 0);
        }
    }

    // ---- bias (x16 prescaled) ----
    float bb[9];
    #pragma unroll
    for (int f = 0; f < 9; ++f) bb[f] = b2s[head * 144 + f * 16 + c];

    // ---- X = fp8(elu(Lq+Pq)) in registers (A-fragment layout) ----
    const int row = w * 16 + c;                        // 0..127
    const unsigned short* pqp = Pq + (size_t)(cp0 + row) * 256;
    const unsigned short* lqp = Lq + (size_t)cl * 256;
    long Xa[8];
    #pragma unroll
    for (int s = 0; s < 8; ++s) {
        u32x4 pv = *(const u32x4*)(pqp + s * 32 + g * 8);
        u32x4 lv = *(const u32x4*)(lqp + s * 32 + g * 8);
        float y0 = eluf(bfhalf_lo(pv[0]) + bfhalf_lo(lv[0]));
        float y1 = eluf(bfhalf_hi(pv[0]) + bfhalf_hi(lv[0]));
        float y2 = eluf(bfhalf_lo(pv[1]) + bfhalf_lo(lv[1]));
        float y3 = eluf(bfhalf_hi(pv[1]) + bfhalf_hi(lv[1]));
        float y4 = eluf(bfhalf_lo(pv[2]) + bfhalf_lo(lv[2]));
        float y5 = eluf(bfhalf_hi(pv[2]) + bfhalf_hi(lv[2]));
        float y6 = eluf(bfhalf_lo(pv[3]) + bfhalf_lo(lv[3]));
        float y7 = eluf(bfhalf_hi(pv[3]) + bfhalf_hi(lv[3]));
        unsigned int lo = (unsigned int)__builtin_amdgcn_cvt_pk_fp8_f32(y0, y1, 0, false);
        lo = (unsigned int)__builtin_amdgcn_cvt_pk_fp8_f32(y2, y3, (int)lo, true);
        unsigned int hi = (unsigned int)__builtin_amdgcn_cvt_pk_fp8_f32(y4, y5, 0, false);
        hi = (unsigned int)__builtin_amdgcn_cvt_pk_fp8_f32(y6, y7, (int)hi, true);
        Xa[s] = (long)(((unsigned long long)hi << 32) | (unsigned long long)lo);
    }

    __syncthreads();    // drains global_load_lds (vmcnt) + barrier

    // ---- K-loop: 36 conflict-free ds_read_b128 + 72 fp8 MFMA / wave ----
    f32x4 acc[9];
    #pragma unroll
    for (int f = 0; f < 9; ++f) acc[f] = (f32x4){bb[f], bb[f], bb[f], bb[f]};

    #pragma unroll
    for (int sp = 0; sp < 4; ++sp) {
        long xa0 = Xa[2 * sp], xa1 = Xa[2 * sp + 1];
        #pragma unroll
        for (int f = 0; f < 9; ++f) {
            u32x4 bq = *(const u32x4*)(Bs + f * 4096 + sp * 1024 + lane * 16);
            long b0 = (long)(((unsigned long long)bq[1] << 32) | (unsigned long long)bq[0]);
            long b1 = (long)(((unsigned long long)bq[3] << 32) | (unsigned long long)bq[2]);
            acc[f] = __builtin_amdgcn_mfma_f32_16x16x32_fp8_fp8(xa0, b0, acc[f], 0, 0, 0);
            acc[f] = __builtin_amdgcn_mfma_f32_16x16x32_fp8_fp8(xa1, b1, acc[f], 0, 0, 0);
        }
    }

    // ---- de-scale ----
    #pragma unroll
    for (int f = 0; f < 9; ++f)
        #pragma unroll
        for (int q = 0; q < 4; ++q) acc[f][q] *= WDESCALE;

    const bool v8 = (c < 12);   // frag 8 covers cols 128..143, valid < 140

    if (head == 0) {
        // ---- pi: softmax over 140 cols, 16-lane-group local ----
        #pragma unroll
        for (int q = 0; q < 4; ++q) {
            float mx = fmaxf(fmaxf(fmaxf(acc[0][q], acc[1][q]), fmaxf(acc[2][q], acc[3][q])),
                             fmaxf(fmaxf(acc[4][q], acc[5][q]), fmaxf(acc[6][q], acc[7][q])));
            if (v8) mx = fmaxf(mx, acc[8][q]);
            mx = fmaxf(mx, __shfl_xor(mx, 1, 64));
            mx = fmaxf(mx, __shfl_xor(mx, 2, 64));
            mx = fmaxf(mx, __shfl_xor(mx, 4, 64));
            mx = fmaxf(mx, __shfl_xor(mx, 8, 64));
            float e0 = __expf(acc[0][q] - mx), e1 = __expf(acc[1][q] - mx);
            float e2 = __expf(acc[2][q] - mx), e3 = __expf(acc[3][q] - mx);
            float e4 = __expf(acc[4][q] - mx), e5 = __expf(acc[5][q] - mx);
            float e6 = __expf(acc[6][q] - mx), e7 = __expf(acc[7][q] - mx);
            float e8 = v8 ? __expf(acc[8][q] - mx) : 0.f;
            float sm = ((e0 + e1) + (e2 + e3)) + ((e4 + e5) + (e6 + e7)) + e8;
            sm += __shfl_xor(sm, 1, 64);
            sm += __shfl_xor(sm, 2, 64);
            sm += __shfl_xor(sm, 4, 64);
            sm += __shfl_xor(sm, 8, 64);
            float inv = 1.f / sm;
            const int gr = m0 + w * 16 + g * 4 + q;
            float* prow = out_pi + (size_t)gr * 140;
            prow[c]       = e0 * inv;  prow[16 + c]  = e1 * inv;
            prow[32 + c]  = e2 * inv;  prow[48 + c]  = e3 * inv;
            prow[64 + c]  = e4 * inv;  prow[80 + c]  = e5 * inv;
            prow[96 + c]  = e6 * inv;  prow[112 + c] = e7 * inv;
            if (v8) prow[128 + c] = e8 * inv;
        }
    } else {
        const float addc = (head == 1) ? 1.1f : 1.0f;
        float* outh = (head == 1) ? out_sig : out_mu;
        #pragma unroll
        for (int q = 0; q < 4; ++q) {
            const int gr = m0 + w * 16 + g * 4 + q;
            float* row = outh + (size_t)gr * 140;
            row[c]       = eluf(acc[0][q]) + addc;
            row[16 + c]  = eluf(acc[1][q]) + addc;
            row[32 + c]  = eluf(acc[2][q]) + addc;
            row[48 + c]  = eluf(acc[3][q]) + addc;
            row[64 + c]  = eluf(acc[4][q]) + addc;
            row[80 + c]  = eluf(acc[5][q]) + addc;
            row[96 + c]  = eluf(acc[6][q]) + addc;
            row[112 + c] = eluf(acc[7][q]) + addc;
            if (v8) row[128 + c] = eluf(acc[8][q]) + addc;
        }
    }
}

// ---------------------------------------------------------------------------
extern "C" void kernel_launch(void* const* d_in, const int* in_sizes, int n_in,
                              void* d_out, int out_size, void* d_ws, size_t ws_size,
                              hipStream_t stream) {
    const float* h_l      = (const float*)d_in[0];
    const float* h_p      = (const float*)d_in[1];
    const float* lig_pos  = (const float*)d_in[2];
    const float* prot_pos = (const float*)d_in[3];
    const int*   esrc     = (const int*)d_in[4];
    const int*   edst     = (const int*)d_in[5];
    const float* W1    = (const float*)d_in[12];
    const float* b1    = (const float*)d_in[13];
    const float* gamma = (const float*)d_in[14];
    const float* beta  = (const float*)d_in[15];
    const float* rmean = (const float*)d_in[16];
    const float* rvar  = (const float*)d_in[17];
    const float* Wpi   = (const float*)d_in[18];
    const float* bpi   = (const float*)d_in[19];
    const float* Wsig  = (const float*)d_in[20];
    const float* bsig  = (const float*)d_in[21];
    const float* Wmu   = (const float*)d_in[22];
    const float* bmu   = (const float*)d_in[23];
    const float* Wat   = (const float*)d_in[24];
    const float* bat   = (const float*)d_in[25];
    const float* Wbt   = (const float*)d_in[26];
    const float* bbt   = (const float*)d_in[27];

    char* ws = (char*)d_ws;
    unsigned short* W1T = (unsigned short*)(ws + 0);
    unsigned char*  W2q = (unsigned char*)(ws + 131072);
    float*          b2s = (float*)(ws + 241664);
    float*          a1v = (float*)(ws + 243392);
    float*          csv = (float*)(ws + 244416);
    unsigned short* Lq  = (unsigned short*)(ws + 245440);
    unsigned short* Pq  = (unsigned short*)(ws + 638656);

    float* out = (float*)d_out;
    const size_t M = M_TOT;
    float* out_pi   = out;
    float* out_sig  = out + M * 140;
    float* out_mu   = out + 2 * M * 140;
    float* out_dist = out + 3 * M * 140;
    float* out_at   = out + 3 * M * 140 + M * 14;
    float* out_bt   = out_at + 768 * 17;
    float* out_pb   = out_bt + 2048 * 5;

    hipLaunchKernelGGL(dist_kernel, dim3(M_TOT / 256), dim3(256), 0, stream,
                       lig_pos, prot_pos, out_dist, out_pb);

    hipLaunchKernelGGL(prep_weights, dim3(432), dim3(256), 0, stream,
                       W1, b1, gamma, beta, rmean, rvar,
                       Wpi, bpi, Wsig, bsig, Wmu, bmu,
                       h_l, esrc, edst, Wat, bat, Wbt, bbt,
                       W1T, W2q, b2s, a1v, csv, out_at, out_bt);

    hipLaunchKernelGGL(node_gemm, dim3(2 * (768 + 6144) / 64), dim3(256), 0, stream,
                       h_l, h_p, W1T, a1v, csv, Lq, Pq);

    hipLaunchKernelGGL(pair_kernel, dim3(M_TOT / 128, 3), dim3(512), 0, stream,
                       Lq, Pq, W2q, b2s, out_pi, out_sig, out_mu);
}